// Round 8
// baseline (229.061 us; speedup 1.0000x reference)
//
#include <hip/hip_runtime.h>

// B=32, T=2048, E=128, fp32. S (B,T,T) never materialized:
//   sx1[b]=sum_t x1[b,t,:], sx2[b]=sum_t x2[b,t,:]
//   w1[t]=x1[b,t].sx2[b]; c1=(1/T) sum_t w1[t]*x2[b,t,:]   (sym. for c2)
//   et1[t]=c1.U1[:,t] + x1[b,t].W1 + b1[t]; softmax; o1=sum_t at1[t]*x1[b,t,:]
// 3 plain launches. R6 measured cg grid.sync at ~70us/sync -> banned.
// R7 measured: shuffle chains in the cold-HBM pass cost ~10us -> K1 stays pure.
// K3 fused into K2 via per-batch last-block (fence + atomic ticket).

#define B_ 32
#define T_ 2048
#define E_ 128
#define EV (E_/4)
#define INV_T (1.0f/2048.0f)

// ws float layout (every slot written before read; counters zeroed by K1)
#define WS_PSX1 0                          // B*16*E  partial sx1
#define WS_PSX2 (B_*16*E_)                 // B*16*E  partial sx2
#define WS_PC1  (2*B_*16*E_)               // B*32*E  partial c1
#define WS_PC2  (2*B_*16*E_ + B_*32*E_)    // B*32*E  partial c2
#define WS_ET1  (2*B_*16*E_ + 2*B_*32*E_)  // B*T  (becomes probabilities)
#define WS_ET2  (WS_ET1 + B_*T_)           // B*T
#define WS_CNT  (WS_ET2 + B_*T_)           // B ints (as float slots)

__device__ __forceinline__ float dot4(float4 a, float4 b) {
    return a.x*b.x + a.y*b.y + a.z*b.z + a.w*b.w;
}
__device__ __forceinline__ void fma4(float4& a, float s, const float4 v) {
    a.x += s*v.x; a.y += s*v.y; a.z += s*v.z; a.w += s*v.w;
}
__device__ __forceinline__ void add4(float4& a, const float4 v) {
    a.x += v.x; a.y += v.y; a.z += v.z; a.w += v.w;
}
__device__ __forceinline__ float bfly32(float v) {
    #pragma unroll
    for (int m = 1; m <= 16; m <<= 1) v += __shfl_xor(v, m);
    return v;   // all 32 lanes hold the sum
}

// ---- K1: pure-streaming partial column sums (proven R5); zero out + counters ----
__global__ __launch_bounds__(256)
void k1_psx(const float* __restrict__ x1, const float* __restrict__ x2,
            float* __restrict__ ws, float* __restrict__ out) {
    __shared__ float4 s_r1[256], s_r2[256];
    const int b = blockIdx.x, g = blockIdx.y, tid = threadIdx.x;
    const float4* p1 = (const float4*)x1 + ((size_t)b*T_ + g*128)*EV;
    const float4* p2 = (const float4*)x2 + ((size_t)b*T_ + g*128)*EV;
    const int rg = tid >> 5, q = tid & 31;
    float4 a1 = {0,0,0,0}, a2 = {0,0,0,0};
    #pragma unroll
    for (int i = 0; i < 16; ++i) {
        int r = i*8 + rg;
        add4(a1, p1[r*EV + q]);
        add4(a2, p2[r*EV + q]);
    }
    s_r1[tid] = a1; s_r2[tid] = a2;
    __syncthreads();
    for (int s = 128; s >= 32; s >>= 1) {
        if (tid < s) { add4(s_r1[tid], s_r1[tid+s]); add4(s_r2[tid], s_r2[tid+s]); }
        __syncthreads();
    }
    if (tid < 32) {
        ((float4*)(ws + WS_PSX1))[(b*16 + g)*EV + tid] = s_r1[tid];
        ((float4*)(ws + WS_PSX2))[(b*16 + g)*EV + tid] = s_r2[tid];
    }
    if (g == 0) {
        out[b*2*E_ + tid] = 0.f;                    // zero output slice
        if (tid == 0) ((int*)(ws + WS_CNT))[b] = 0; // zero batch ticket counter
    }
}

// ---- K2: R5's reg-tiled w/c/et kernel + fused per-batch last-block K3 tail ----
__global__ __launch_bounds__(256)
void k2_wc_et(const float* __restrict__ x1, const float* __restrict__ x2,
              const float* __restrict__ W1, const float* __restrict__ b1,
              const float* __restrict__ U1, const float* __restrict__ W2,
              const float* __restrict__ b2, const float* __restrict__ U2,
              float* __restrict__ ws, float* __restrict__ out) {
    __shared__ float4 s_r1[256], s_r2[256];                  // reduce / red scratch
    __shared__ float  s_a[E_], s_b[E_], s_wa[E_], s_wb[E_];  // sx1,sx2,W1,W2 -> c1,c2
    __shared__ float  s_w1[64], s_w2[64];
    __shared__ int    s_ticket;
    const int b = blockIdx.x, ch = blockIdx.y, tid = threadIdx.x;
    if (tid < E_) {
        float sa = 0.f, sb = 0.f;
        #pragma unroll
        for (int g = 0; g < 16; ++g) {
            sa += ws[WS_PSX1 + (b*16 + g)*E_ + tid];
            sb += ws[WS_PSX2 + (b*16 + g)*E_ + tid];
        }
        s_a[tid] = sa; s_b[tid] = sb;
        s_wa[tid] = W1[tid]; s_wb[tid] = W2[tid];
    }
    __syncthreads();
    const float4* p1 = (const float4*)x1 + ((size_t)b*T_ + ch*64)*EV;
    const float4* p2 = (const float4*)x2 + ((size_t)b*T_ + ch*64)*EV;
    const float4* sx1v = (const float4*)s_a;
    const float4* sx2v = (const float4*)s_b;
    const float4* W1v  = (const float4*)s_wa;
    const float4* W2v  = (const float4*)s_wb;
    const int rowoff = tid >> 5, q = tid & 31;

    // tile loaded once into registers; reused by both phases (proven R5)
    float4 v1[8], v2[8];
    #pragma unroll
    for (int i = 0; i < 8; ++i) {
        int r = i*8 + rowoff;
        v1[i] = p1[r*EV + q];
        v2[i] = p2[r*EV + q];
    }

    float* et1 = ws + WS_ET1 + (size_t)b*T_ + ch*64;
    float* et2 = ws + WS_ET2 + (size_t)b*T_ + ch*64;
    #pragma unroll
    for (int i = 0; i < 8; ++i) {
        int r = i*8 + rowoff;
        float pw1 = bfly32(dot4(v1[i], sx2v[q]));    // x1 . sx2
        float px1 = bfly32(dot4(v1[i], W1v[q]));     // x1 . W1
        float pw2 = bfly32(dot4(v2[i], sx1v[q]));    // x2 . sx1
        float px2 = bfly32(dot4(v2[i], W2v[q]));     // x2 . W2
        if (q == 0) {
            s_w1[r] = pw1; s_w2[r] = pw2;
            int trow = ch*64 + r;
            et1[r] = px1 + b1[trow];
            et2[r] = px2 + b2[trow];
        }
    }
    __syncthreads();

    float4 a1 = {0,0,0,0}, a2 = {0,0,0,0};
    #pragma unroll
    for (int i = 0; i < 8; ++i) {
        int r = i*8 + rowoff;
        fma4(a1, s_w1[r], v2[i]);
        fma4(a2, s_w2[r], v1[i]);
    }
    s_r1[tid] = a1; s_r2[tid] = a2;
    __syncthreads();
    for (int s = 128; s >= 32; s >>= 1) {
        if (tid < s) { add4(s_r1[tid], s_r1[tid+s]); add4(s_r2[tid], s_r2[tid+s]); }
        __syncthreads();
    }
    if (tid < 32) {
        float4 t1 = s_r1[tid], t2 = s_r2[tid];
        t1.x *= INV_T; t1.y *= INV_T; t1.z *= INV_T; t1.w *= INV_T;
        t2.x *= INV_T; t2.y *= INV_T; t2.z *= INV_T; t2.w *= INV_T;
        ((float4*)(ws + WS_PC1))[(b*32 + ch)*EV + tid] = t1;
        ((float4*)(ws + WS_PC2))[(b*32 + ch)*EV + tid] = t2;
    }

    // ---- completion ticket: last block of this batch runs the K3 tail ----
    __threadfence();                      // release: pc + et stores device-visible
    __syncthreads();                      // all threads' fences done
    if (tid == 0) s_ticket = atomicAdd(&((int*)(ws + WS_CNT))[b], 1);
    __syncthreads();
    if (s_ticket != 31) return;
    __threadfence();                      // acquire: see other blocks' pc/et

    // reduce c partials into s_a (c1) / s_b (c2)  [sx no longer needed]
    if (tid < 128) {
        float s = 0.f;
        #pragma unroll
        for (int cc = 0; cc < 32; ++cc) s += ws[WS_PC1 + (b*32 + cc)*E_ + tid];
        s_a[tid] = s;
    } else {
        float s = 0.f;
        #pragma unroll
        for (int cc = 0; cc < 32; ++cc) s += ws[WS_PC2 + (b*32 + cc)*E_ + (tid-128)];
        s_b[tid - 128] = s;
    }
    __syncthreads();

    float* red = (float*)s_r1;            // 256-float scratch
    #pragma unroll
    for (int sel = 0; sel < 2; ++sel) {
        const float4* U4 = (const float4*)(sel ? U2 : U1);   // E x 512
        const float*  cv = sel ? s_b : s_a;
        float4* et4 = (float4*)(ws + (sel ? WS_ET2 : WS_ET1) + (size_t)b*T_);
        float4 a0 = et4[tid], a1t = et4[tid + 256];          // et init (x.W + b)
        float4 b0 = {0,0,0,0}, b1t = {0,0,0,0};
        #pragma unroll 4
        for (int e = 0; e < E_; e += 2) {                    // 2 independent chains
            float c0 = cv[e], c1 = cv[e+1];
            fma4(a0,  c0, U4[(size_t)(e  )*(T_/4) + tid]);
            fma4(a1t, c0, U4[(size_t)(e  )*(T_/4) + tid + 256]);
            fma4(b0,  c1, U4[(size_t)(e+1)*(T_/4) + tid]);
            fma4(b1t, c1, U4[(size_t)(e+1)*(T_/4) + tid + 256]);
        }
        add4(a0, b0); add4(a1t, b1t);
        float m = fmaxf(fmaxf(fmaxf(a0.x, a0.y),  fmaxf(a0.z, a0.w)),
                        fmaxf(fmaxf(a1t.x, a1t.y), fmaxf(a1t.z, a1t.w)));
        red[tid] = m; __syncthreads();
        for (int s = 128; s > 0; s >>= 1) {
            if (tid < s) red[tid] = fmaxf(red[tid], red[tid+s]);
            __syncthreads();
        }
        m = red[0]; __syncthreads();
        float4 e0, e1;
        e0.x = __expf(a0.x - m);  e0.y = __expf(a0.y - m);
        e0.z = __expf(a0.z - m);  e0.w = __expf(a0.w - m);
        e1.x = __expf(a1t.x - m); e1.y = __expf(a1t.y - m);
        e1.z = __expf(a1t.z - m); e1.w = __expf(a1t.w - m);
        red[tid] = e0.x + e0.y + e0.z + e0.w + e1.x + e1.y + e1.z + e1.w;
        __syncthreads();
        for (int s = 128; s > 0; s >>= 1) {
            if (tid < s) red[tid] += red[tid+s];
            __syncthreads();
        }
        float il = 1.f / red[0];
        e0.x *= il; e0.y *= il; e0.z *= il; e0.w *= il;
        e1.x *= il; e1.y *= il; e1.z *= il; e1.w *= il;
        et4[tid]       = e0;                                 // et now holds at[t]
        et4[tid + 256] = e1;
        __syncthreads();                                     // red reuse guard
    }
}

// ---- K5: o = sum_t at[t]*x[t,:] (proven R5) ----
__global__ __launch_bounds__(256)
void k5_out(const float* __restrict__ x1, const float* __restrict__ x2,
            const float* __restrict__ ws, float* __restrict__ out) {
    __shared__ float4 s_r1[256], s_r2[256];
    __shared__ float s_p1[128], s_p2[128];
    const int b = blockIdx.x, g = blockIdx.y, tid = threadIdx.x;
    const float* pr1 = ws + WS_ET1 + (size_t)b*T_ + g*128;
    const float* pr2 = ws + WS_ET2 + (size_t)b*T_ + g*128;
    if (tid < 128) s_p1[tid] = pr1[tid];
    else           s_p2[tid - 128] = pr2[tid - 128];
    __syncthreads();
    const float4* p1 = (const float4*)x1 + ((size_t)b*T_ + g*128)*EV;
    const float4* p2 = (const float4*)x2 + ((size_t)b*T_ + g*128)*EV;
    const int rg = tid >> 5, q = tid & 31;
    float4 a1 = {0,0,0,0}, a2 = {0,0,0,0};
    #pragma unroll
    for (int i = 0; i < 16; ++i) {
        int r = i*8 + rg;
        fma4(a1, s_p1[r], p1[r*EV + q]);
        fma4(a2, s_p2[r], p2[r*EV + q]);
    }
    s_r1[tid] = a1; s_r2[tid] = a2;
    __syncthreads();
    for (int s = 128; s >= 32; s >>= 1) {
        if (tid < s) { add4(s_r1[tid], s_r1[tid+s]); add4(s_r2[tid], s_r2[tid+s]); }
        __syncthreads();
    }
    if (tid < 32) {
        float4 t1 = s_r1[tid], t2 = s_r2[tid];
        atomicAdd(&out[b*2*E_ + tid*4+0], t1.x);
        atomicAdd(&out[b*2*E_ + tid*4+1], t1.y);
        atomicAdd(&out[b*2*E_ + tid*4+2], t1.z);
        atomicAdd(&out[b*2*E_ + tid*4+3], t1.w);
        atomicAdd(&out[b*2*E_ + E_ + tid*4+0], t2.x);
        atomicAdd(&out[b*2*E_ + E_ + tid*4+1], t2.y);
        atomicAdd(&out[b*2*E_ + E_ + tid*4+2], t2.z);
        atomicAdd(&out[b*2*E_ + E_ + tid*4+3], t2.w);
    }
}

extern "C" void kernel_launch(void* const* d_in, const int* in_sizes, int n_in,
                              void* d_out, int out_size, void* d_ws, size_t ws_size,
                              hipStream_t stream) {
    const float* x1 = (const float*)d_in[0];
    const float* x2 = (const float*)d_in[1];
    const float* W1 = (const float*)d_in[2];
    const float* b1 = (const float*)d_in[3];
    const float* U1 = (const float*)d_in[4];
    const float* W2 = (const float*)d_in[5];
    const float* b2 = (const float*)d_in[6];
    const float* U2 = (const float*)d_in[7];
    float* ws  = (float*)d_ws;
    float* out = (float*)d_out;

    k1_psx<<<dim3(B_, 16), 256, 0, stream>>>(x1, x2, ws, out);
    k2_wc_et<<<dim3(B_, 32), 256, 0, stream>>>(x1, x2, W1, b1, U1, W2, b2, U2, ws, out);
    k5_out<<<dim3(B_, 16), 256, 0, stream>>>(x1, x2, ws, out);
}

// Round 9
// 146.782 us; speedup vs baseline: 1.5606x; 1.5606x over previous
//
#include <hip/hip_runtime.h>

// B=32, T=2048, E=128, fp32. S (B,T,T) never materialized:
//   sx1[b]=sum_t x1[b,t,:], sx2[b]=sum_t x2[b,t,:]
//   w1[t]=x1[b,t].sx2[b]; c1=(1/T) sum_t w1[t]*x2[b,t,:]   (sym. for c2)
//   et1[t]=c1.U1[:,t] + x1[b,t].W1 + b1[t]; softmax; o1=sum_t at1[t]*x1[b,t,:]
// 4 plain launches (R5 structure, best measured: 148.9us).
// Measured bans: cg grid.sync ~70us/sync (R6); per-block __threadfence storm
// ~90us (R8); shuffle chains in the cold-HBM pass +10us (R7).

#define B_ 32
#define T_ 2048
#define E_ 128
#define EV (E_/4)
#define INV_T (1.0f/2048.0f)

// ws float layout (every slot written before read -> no zeroing needed)
#define WS_PSX1 0                          // B*16*E  partial sx1
#define WS_PSX2 (B_*16*E_)                 // B*16*E  partial sx2
#define WS_PC1  (2*B_*16*E_)               // B*32*E  partial c1
#define WS_PC2  (2*B_*16*E_ + B_*32*E_)    // B*32*E  partial c2
#define WS_ET1  (2*B_*16*E_ + 2*B_*32*E_)  // B*T  (becomes probabilities)
#define WS_ET2  (WS_ET1 + B_*T_)           // B*T

__device__ __forceinline__ float dot4(float4 a, float4 b) {
    return a.x*b.x + a.y*b.y + a.z*b.z + a.w*b.w;
}
__device__ __forceinline__ void fma4(float4& a, float s, const float4 v) {
    a.x += s*v.x; a.y += s*v.y; a.z += s*v.z; a.w += s*v.w;
}
__device__ __forceinline__ void add4(float4& a, const float4 v) {
    a.x += v.x; a.y += v.y; a.z += v.z; a.w += v.w;
}
__device__ __forceinline__ float bfly32(float v) {
    #pragma unroll
    for (int m = 1; m <= 16; m <<= 1) v += __shfl_xor(v, m);
    return v;   // all 32 lanes hold the sum
}

// ---- K1: pure-streaming partial column sums (proven R5; no shuffles here) ----
__global__ __launch_bounds__(256)
void k1_psx(const float* __restrict__ x1, const float* __restrict__ x2,
            float* __restrict__ ws) {
    __shared__ float4 s_r1[256], s_r2[256];
    const int b = blockIdx.x, g = blockIdx.y, tid = threadIdx.x;
    const float4* p1 = (const float4*)x1 + ((size_t)b*T_ + g*128)*EV;
    const float4* p2 = (const float4*)x2 + ((size_t)b*T_ + g*128)*EV;
    const int rg = tid >> 5, q = tid & 31;
    float4 a1 = {0,0,0,0}, a2 = {0,0,0,0};
    #pragma unroll
    for (int i = 0; i < 16; ++i) {
        int r = i*8 + rg;
        add4(a1, p1[r*EV + q]);
        add4(a2, p2[r*EV + q]);
    }
    s_r1[tid] = a1; s_r2[tid] = a2;
    __syncthreads();
    for (int s = 128; s >= 32; s >>= 1) {
        if (tid < s) { add4(s_r1[tid], s_r1[tid+s]); add4(s_r2[tid], s_r2[tid+s]); }
        __syncthreads();
    }
    if (tid < 32) {
        ((float4*)(ws + WS_PSX1))[(b*16 + g)*EV + tid] = s_r1[tid];
        ((float4*)(ws + WS_PSX2))[(b*16 + g)*EV + tid] = s_r2[tid];
    }
}

// ---- K2: reduce psx, reg-tiled row weights + x.W logits + c partials (proven R5) ----
__global__ __launch_bounds__(256)
void k2_wc(const float* __restrict__ x1, const float* __restrict__ x2,
           const float* __restrict__ W1, const float* __restrict__ b1,
           const float* __restrict__ W2, const float* __restrict__ b2,
           float* __restrict__ ws) {
    __shared__ float4 s_r1[256], s_r2[256];
    __shared__ float  s_a[E_], s_b[E_], s_wa[E_], s_wb[E_];
    __shared__ float  s_w1[64], s_w2[64];
    const int b = blockIdx.x, ch = blockIdx.y, tid = threadIdx.x;
    if (tid < E_) {
        float sa = 0.f, sb = 0.f;
        #pragma unroll
        for (int g = 0; g < 16; ++g) {
            sa += ws[WS_PSX1 + (b*16 + g)*E_ + tid];
            sb += ws[WS_PSX2 + (b*16 + g)*E_ + tid];
        }
        s_a[tid] = sa; s_b[tid] = sb;
        s_wa[tid] = W1[tid]; s_wb[tid] = W2[tid];
    }
    __syncthreads();
    const float4* p1 = (const float4*)x1 + ((size_t)b*T_ + ch*64)*EV;
    const float4* p2 = (const float4*)x2 + ((size_t)b*T_ + ch*64)*EV;
    const float4* sx1v = (const float4*)s_a;
    const float4* sx2v = (const float4*)s_b;
    const float4* W1v  = (const float4*)s_wa;
    const float4* W2v  = (const float4*)s_wb;
    const int rowoff = tid >> 5, q = tid & 31;

    // tile loaded once into registers; reused by both phases
    float4 v1[8], v2[8];
    #pragma unroll
    for (int i = 0; i < 8; ++i) {
        int r = i*8 + rowoff;
        v1[i] = p1[r*EV + q];
        v2[i] = p2[r*EV + q];
    }

    float* et1 = ws + WS_ET1 + (size_t)b*T_ + ch*64;
    float* et2 = ws + WS_ET2 + (size_t)b*T_ + ch*64;
    #pragma unroll
    for (int i = 0; i < 8; ++i) {
        int r = i*8 + rowoff;
        float pw1 = bfly32(dot4(v1[i], sx2v[q]));    // x1 . sx2
        float px1 = bfly32(dot4(v1[i], W1v[q]));     // x1 . W1
        float pw2 = bfly32(dot4(v2[i], sx1v[q]));    // x2 . sx1
        float px2 = bfly32(dot4(v2[i], W2v[q]));     // x2 . W2
        if (q == 0) {
            s_w1[r] = pw1; s_w2[r] = pw2;
            int trow = ch*64 + r;
            et1[r] = px1 + b1[trow];
            et2[r] = px2 + b2[trow];
        }
    }
    __syncthreads();

    float4 a1 = {0,0,0,0}, a2 = {0,0,0,0};
    #pragma unroll
    for (int i = 0; i < 8; ++i) {
        int r = i*8 + rowoff;
        fma4(a1, s_w1[r], v2[i]);
        fma4(a2, s_w2[r], v1[i]);
    }
    s_r1[tid] = a1; s_r2[tid] = a2;
    __syncthreads();
    for (int s = 128; s >= 32; s >>= 1) {
        if (tid < s) { add4(s_r1[tid], s_r1[tid+s]); add4(s_r2[tid], s_r2[tid+s]); }
        __syncthreads();
    }
    if (tid < 32) {
        float4 t1 = s_r1[tid], t2 = s_r2[tid];
        t1.x *= INV_T; t1.y *= INV_T; t1.z *= INV_T; t1.w *= INV_T;
        t2.x *= INV_T; t2.y *= INV_T; t2.z *= INV_T; t2.w *= INV_T;
        ((float4*)(ws + WS_PC1))[(b*32 + ch)*EV + tid] = t1;
        ((float4*)(ws + WS_PC2))[(b*32 + ch)*EV + tid] = t2;
    }
}

// ---- K3: reduce c, et += c.U (4 indep chains), softmax -> probs; zero out ----
__global__ __launch_bounds__(512)
void k3_et_softmax(const float* __restrict__ U1, const float* __restrict__ U2,
                   float* __restrict__ ws, float* __restrict__ out) {
    __shared__ float s_c[E_];
    __shared__ float red[512];
    const int b = blockIdx.x, sel = blockIdx.y, tid = threadIdx.x;
    const float* U = sel ? U2 : U1;
    const float* pc = ws + (sel ? WS_PC2 : WS_PC1);
    float4* et4 = (float4*)(ws + (sel ? WS_ET2 : WS_ET1) + (size_t)b*T_);
    if (tid < E_) {
        float s = 0.f;
        #pragma unroll
        for (int ch = 0; ch < 32; ++ch) s += pc[(b*32 + ch)*E_ + tid];
        s_c[tid] = s;
    } else if (tid >= 256 && tid < 256 + E_) {
        out[b*2*E_ + sel*E_ + (tid - 256)] = 0.f;
    }
    __syncthreads();
    const float4* U4 = (const float4*)U;           // E x 512
    float4 accA = et4[tid];                        // et init (x.W + b)
    float4 accB = {0,0,0,0}, accC = {0,0,0,0}, accD = {0,0,0,0};
    #pragma unroll 2
    for (int e = 0; e < E_; e += 4) {              // 4 independent load/FMA chains
        fma4(accA, s_c[e+0], U4[(size_t)(e+0)*(T_/4) + tid]);
        fma4(accB, s_c[e+1], U4[(size_t)(e+1)*(T_/4) + tid]);
        fma4(accC, s_c[e+2], U4[(size_t)(e+2)*(T_/4) + tid]);
        fma4(accD, s_c[e+3], U4[(size_t)(e+3)*(T_/4) + tid]);
    }
    add4(accA, accB); add4(accC, accD); add4(accA, accC);
    float m = fmaxf(fmaxf(accA.x, accA.y), fmaxf(accA.z, accA.w));
    red[tid] = m; __syncthreads();
    for (int s = 256; s > 0; s >>= 1) {
        if (tid < s) red[tid] = fmaxf(red[tid], red[tid+s]);
        __syncthreads();
    }
    m = red[0]; __syncthreads();
    float4 e4;
    e4.x = __expf(accA.x - m); e4.y = __expf(accA.y - m);
    e4.z = __expf(accA.z - m); e4.w = __expf(accA.w - m);
    red[tid] = e4.x + e4.y + e4.z + e4.w;
    __syncthreads();
    for (int s = 256; s > 0; s >>= 1) {
        if (tid < s) red[tid] += red[tid+s];
        __syncthreads();
    }
    float il = 1.f / red[0];
    e4.x *= il; e4.y *= il; e4.z *= il; e4.w *= il;
    et4[tid] = e4;                                 // et now holds at[t]
}

// ---- K5: o = sum_t at[t]*x[t,:] (proven R5) ----
__global__ __launch_bounds__(256)
void k5_out(const float* __restrict__ x1, const float* __restrict__ x2,
            const float* __restrict__ ws, float* __restrict__ out) {
    __shared__ float4 s_r1[256], s_r2[256];
    __shared__ float s_p1[128], s_p2[128];
    const int b = blockIdx.x, g = blockIdx.y, tid = threadIdx.x;
    const float* pr1 = ws + WS_ET1 + (size_t)b*T_ + g*128;
    const float* pr2 = ws + WS_ET2 + (size_t)b*T_ + g*128;
    if (tid < 128) s_p1[tid] = pr1[tid];
    else           s_p2[tid - 128] = pr2[tid - 128];
    __syncthreads();
    const float4* p1 = (const float4*)x1 + ((size_t)b*T_ + g*128)*EV;
    const float4* p2 = (const float4*)x2 + ((size_t)b*T_ + g*128)*EV;
    const int rg = tid >> 5, q = tid & 31;
    float4 a1 = {0,0,0,0}, a2 = {0,0,0,0};
    #pragma unroll
    for (int i = 0; i < 16; ++i) {
        int r = i*8 + rg;
        fma4(a1, s_p1[r], p1[r*EV + q]);
        fma4(a2, s_p2[r], p2[r*EV + q]);
    }
    s_r1[tid] = a1; s_r2[tid] = a2;
    __syncthreads();
    for (int s = 128; s >= 32; s >>= 1) {
        if (tid < s) { add4(s_r1[tid], s_r1[tid+s]); add4(s_r2[tid], s_r2[tid+s]); }
        __syncthreads();
    }
    if (tid < 32) {
        float4 t1 = s_r1[tid], t2 = s_r2[tid];
        atomicAdd(&out[b*2*E_ + tid*4+0], t1.x);
        atomicAdd(&out[b*2*E_ + tid*4+1], t1.y);
        atomicAdd(&out[b*2*E_ + tid*4+2], t1.z);
        atomicAdd(&out[b*2*E_ + tid*4+3], t1.w);
        atomicAdd(&out[b*2*E_ + E_ + tid*4+0], t2.x);
        atomicAdd(&out[b*2*E_ + E_ + tid*4+1], t2.y);
        atomicAdd(&out[b*2*E_ + E_ + tid*4+2], t2.z);
        atomicAdd(&out[b*2*E_ + E_ + tid*4+3], t2.w);
    }
}

extern "C" void kernel_launch(void* const* d_in, const int* in_sizes, int n_in,
                              void* d_out, int out_size, void* d_ws, size_t ws_size,
                              hipStream_t stream) {
    const float* x1 = (const float*)d_in[0];
    const float* x2 = (const float*)d_in[1];
    const float* W1 = (const float*)d_in[2];
    const float* b1 = (const float*)d_in[3];
    const float* U1 = (const float*)d_in[4];
    const float* W2 = (const float*)d_in[5];
    const float* b2 = (const float*)d_in[6];
    const float* U2 = (const float*)d_in[7];
    float* ws  = (float*)d_ws;
    float* out = (float*)d_out;

    k1_psx<<<dim3(B_, 16), 256, 0, stream>>>(x1, x2, ws);
    k2_wc<<<dim3(B_, 32), 256, 0, stream>>>(x1, x2, W1, b1, W2, b2, ws);
    k3_et_softmax<<<dim3(B_, 2), 512, 0, stream>>>(U1, U2, ws, out);
    k5_out<<<dim3(B_, 16), 256, 0, stream>>>(x1, x2, ws, out);
}